// Round 13
// baseline (188.744 us; speedup 1.0000x reference)
//
#include <hip/hip_runtime.h>
#include <cstdio>
#include <cstdint>

// Problem constants
#define BATCH 8
#define CH    512
#define OC3   1536      // 3*CH
#define NPIX  4096      // 64*64
#define HEADS 8
#define HDIM  64
#define KDEPTH 512      // GEMM K for 512-deep GEMMs
#define SCALE 0.125f    // 64^-0.5
#define GSPLIT 4        // split-K for Gram (1024 n per split)

typedef __bf16 bf16;
typedef __bf16 bf16x4 __attribute__((ext_vector_type(4)));
typedef __bf16 bf16x8 __attribute__((ext_vector_type(8)));
typedef float  f32x4  __attribute__((ext_vector_type(4)));

#define AS1 __attribute__((address_space(1)))
#define AS3 __attribute__((address_space(3)))

// ---------------------------------------------------------------------------
// fp32 -> bf16 flat convert (weights)
// ---------------------------------------------------------------------------
__global__ __launch_bounds__(256) void convert_bf16_kernel(
    const float* __restrict__ in, bf16* __restrict__ out, int n)
{
    const int i = blockIdx.x * 256 + threadIdx.x;
    if (i < n) out[i] = (bf16)in[i];
}

// ---------------------------------------------------------------------------
// x [b][512][4096] fp32 -> xt [b][4096][512] bf16 (transpose)  AND
//                          xb [b][512][4096] bf16 (flat convert)
// ---------------------------------------------------------------------------
__global__ __launch_bounds__(256) void transpose_convert_dual_kernel(
    const float* __restrict__ x, bf16* __restrict__ xt, bf16* __restrict__ xb)
{
    const int b  = blockIdx.z;
    const int n0 = blockIdx.x * 64;
    const int c0 = blockIdx.y * 64;
    __shared__ float tile[64][65];
    const int t = threadIdx.x;
    const float* xp = x + (size_t)b * CH * NPIX;

    #pragma unroll
    for (int i = 0; i < 4; ++i) {
        const int lin = t + 256 * i;
        const int r   = lin >> 4;          // c-local
        const int c4  = (lin & 15) * 4;    // n-local
        const float4 v = *(const float4*)(xp + (size_t)(c0 + r) * 4096 + n0 + c4);
        tile[r][c4 + 0] = v.x; tile[r][c4 + 1] = v.y;
        tile[r][c4 + 2] = v.z; tile[r][c4 + 3] = v.w;
    }
    __syncthreads();

    bf16* op = xt + (size_t)b * NPIX * CH;
    bf16* fb = xb + (size_t)b * CH * NPIX;
    #pragma unroll
    for (int i = 0; i < 2; ++i) {
        const int lin = t + 256 * i;       // 0..511
        {
            const int n  = lin >> 3;
            const int c8 = (lin & 7) * 8;
            bf16x8 v;
            #pragma unroll
            for (int jj = 0; jj < 8; ++jj) v[jj] = (bf16)tile[c8 + jj][n];
            *(bf16x8*)(op + (size_t)(n0 + n) * CH + c0 + c8) = v;
        }
        {
            const int r  = lin >> 3;
            const int n8 = (lin & 7) * 8;
            bf16x8 v;
            #pragma unroll
            for (int jj = 0; jj < 8; ++jj) v[jj] = (bf16)tile[r][n8 + jj];
            *(bf16x8*)(fb + (size_t)(c0 + r) * NPIX + n0 + n8) = v;
        }
    }
}

// ---------------------------------------------------------------------------
// xsum[b][c] = sum_n x[b][c][n]   (fp32, exact)
// ---------------------------------------------------------------------------
__global__ __launch_bounds__(256) void xsum_kernel(
    const float* __restrict__ x, float* __restrict__ xs)
{
    const int bc = blockIdx.x;             // 0..4095
    const float* row = x + (size_t)bc * 4096;
    const int t = threadIdx.x;
    float s = 0.f;
    #pragma unroll
    for (int j = 0; j < 16; ++j) s += row[t + 256 * j];
    #pragma unroll
    for (int off = 1; off < 64; off <<= 1) s += __shfl_xor(s, off);
    __shared__ float wsum[4];
    if ((t & 63) == 0) wsum[t >> 6] = s;
    __syncthreads();
    if (t == 0) xs[bc] = wsum[0] + wsum[1] + wsum[2] + wsum[3];
}

// ---------------------------------------------------------------------------
// Gram split-K partial: gpart[b*4+s][m][n] = sum_{n' in split} xb[m,n']xb[n,n']
// ---------------------------------------------------------------------------
__global__ __launch_bounds__(256) void gram_partial_kernel(
    const bf16* __restrict__ xb, float* __restrict__ gpart)
{
    const int bs = blockIdx.z;
    const int b = bs >> 2, s = bs & 3;
    const int m0 = blockIdx.y * 128;
    const int n0 = blockIdx.x * 128;
    const bf16* Xp = xb + (size_t)b * CH * NPIX;
    const int kbase = s * 1024;

    __shared__ bf16 smem[16384];

    const int t    = threadIdx.x;
    const int lane = t & 63;
    const int wave = t >> 6;
    const int wr   = wave >> 1, wc = wave & 1;

    f32x4 acc[4][4];
    const f32x4 zf = {0.f, 0.f, 0.f, 0.f};
    #pragma unroll
    for (int i = 0; i < 4; ++i)
        #pragma unroll
        for (int j = 0; j < 4; ++j) acc[i][j] = zf;

    auto STAGE = [&](int p, int k0) {
        #pragma unroll
        for (int i = 0; i < 2; ++i) {
            const int c   = t + 256 * i;
            const int row = c >> 2;
            const int kb  = ((c & 3) ^ ((row >> 1) & 3)) * 8;
            __builtin_amdgcn_global_load_lds(
                (const AS1 void*)(Xp + (size_t)(m0 + row) * NPIX + kbase + k0 + kb),
                (AS3 void*)(smem + p * 8192 + c * 8), 16, 0, 0);
            __builtin_amdgcn_global_load_lds(
                (const AS1 void*)(Xp + (size_t)(n0 + row) * NPIX + kbase + k0 + kb),
                (AS3 void*)(smem + p * 8192 + 4096 + c * 8), 16, 0, 0);
        }
    };

    STAGE(0, 0);
    __syncthreads();
    int cur = 0;

    for (int kt = 0; kt < 1024 / 32; ++kt) {
        if (kt < 1024 / 32 - 1) STAGE(cur ^ 1, (kt + 1) * 32);

        const bf16* AsP = smem + cur * 8192;
        const bf16* BsP = AsP + 4096;
        bf16x8 af[4], bfv[4];
        #pragma unroll
        for (int i = 0; i < 4; ++i) {
            const int ar = wr * 64 + i * 16 + (lane & 15);
            const int ja = (lane >> 4) ^ ((ar >> 1) & 3);
            af[i]  = *(const bf16x8*)(AsP + ar * 32 + ja * 8);
            const int br = wc * 64 + i * 16 + (lane & 15);
            const int jb = (lane >> 4) ^ ((br >> 1) & 3);
            bfv[i] = *(const bf16x8*)(BsP + br * 32 + jb * 8);
        }
        #pragma unroll
        for (int i = 0; i < 4; ++i)
            #pragma unroll
            for (int j = 0; j < 4; ++j)
                acc[i][j] = __builtin_amdgcn_mfma_f32_16x16x32_bf16(
                    af[i], bfv[j], acc[i][j], 0, 0, 0);

        __syncthreads();
        cur ^= 1;
    }

    float* Gp = gpart + (size_t)bs * CH * CH;
    #pragma unroll
    for (int i = 0; i < 4; ++i) {
        const int mb = m0 + wr * 64 + i * 16 + (lane >> 4) * 4;
        #pragma unroll
        for (int r = 0; r < 4; ++r) {
            const int m = mb + r;
            #pragma unroll
            for (int j = 0; j < 4; ++j) {
                const int n = n0 + wc * 64 + j * 16 + (lane & 15);
                Gp[(size_t)m * CH + n] = acc[i][j][r];
            }
        }
    }
}

// ---------------------------------------------------------------------------
// Gpair[b][n][0..511]=hi, [512..1023]=lo  of  sum_s gpart  (hi/lo bf16 pair)
// ---------------------------------------------------------------------------
__global__ __launch_bounds__(256) void gram_reduce_kernel(
    const float* __restrict__ gpart, bf16* __restrict__ Gpair)
{
    const int gi = blockIdx.x * 256 + threadIdx.x;   // < 8*262144
    const int b = gi >> 18, r = gi & 262143;
    const int n = r >> 9, k = r & 511;
    const float* p = gpart + (size_t)(b * 4) * 262144 + r;
    const float s = p[0] + p[262144] + p[2 * 262144] + p[3 * 262144];
    const bf16 hi = (bf16)s;
    const bf16 lo = (bf16)(s - (float)hi);
    bf16* gp = Gpair + ((size_t)b * CH + n) * 1024;
    gp[k] = hi;
    gp[512 + k] = lo;
}

// ---------------------------------------------------------------------------
// T2 = Wq · (Ghi + Glo): K=1024 GEMM (A k-index masked &511), output hi/lo
// bf16 pair T2pair[b][m][0..511]=hi, [512..1023]=lo.  Uses G symmetry.
// ---------------------------------------------------------------------------
__global__ __launch_bounds__(256) void t2_gemm_kernel(
    const bf16* __restrict__ Wq, const bf16* __restrict__ Gpair,
    bf16* __restrict__ T2pair)
{
    const int b  = blockIdx.z;
    const int m0 = blockIdx.y * 128;
    const int n0 = blockIdx.x * 128;
    const bf16* Bp = Gpair + (size_t)b * CH * 1024;

    __shared__ bf16 smem[16384];

    const int t    = threadIdx.x;
    const int lane = t & 63;
    const int wave = t >> 6;
    const int wr   = wave >> 1, wc = wave & 1;

    f32x4 acc[4][4];
    const f32x4 zf = {0.f, 0.f, 0.f, 0.f};
    #pragma unroll
    for (int i = 0; i < 4; ++i)
        #pragma unroll
        for (int j = 0; j < 4; ++j) acc[i][j] = zf;

    auto STAGE = [&](int p, int k0) {
        #pragma unroll
        for (int i = 0; i < 2; ++i) {
            const int c   = t + 256 * i;
            const int row = c >> 2;
            const int kb  = ((c & 3) ^ ((row >> 1) & 3)) * 8;
            __builtin_amdgcn_global_load_lds(
                (const AS1 void*)(Wq + (size_t)(m0 + row) * KDEPTH + ((k0 + kb) & 511)),
                (AS3 void*)(smem + p * 8192 + c * 8), 16, 0, 0);
            __builtin_amdgcn_global_load_lds(
                (const AS1 void*)(Bp + (size_t)(n0 + row) * 1024 + k0 + kb),
                (AS3 void*)(smem + p * 8192 + 4096 + c * 8), 16, 0, 0);
        }
    };

    STAGE(0, 0);
    __syncthreads();
    int cur = 0;

    for (int kt = 0; kt < 1024 / 32; ++kt) {
        if (kt < 1024 / 32 - 1) STAGE(cur ^ 1, (kt + 1) * 32);

        const bf16* AsP = smem + cur * 8192;
        const bf16* BsP = AsP + 4096;
        bf16x8 af[4], bfv[4];
        #pragma unroll
        for (int i = 0; i < 4; ++i) {
            const int ar = wr * 64 + i * 16 + (lane & 15);
            const int ja = (lane >> 4) ^ ((ar >> 1) & 3);
            af[i]  = *(const bf16x8*)(AsP + ar * 32 + ja * 8);
            const int br = wc * 64 + i * 16 + (lane & 15);
            const int jb = (lane >> 4) ^ ((br >> 1) & 3);
            bfv[i] = *(const bf16x8*)(BsP + br * 32 + jb * 8);
        }
        #pragma unroll
        for (int i = 0; i < 4; ++i)
            #pragma unroll
            for (int j = 0; j < 4; ++j)
                acc[i][j] = __builtin_amdgcn_mfma_f32_16x16x32_bf16(
                    af[i], bfv[j], acc[i][j], 0, 0, 0);

        __syncthreads();
        cur ^= 1;
    }

    bf16* Tp = T2pair + (size_t)b * CH * 1024;
    #pragma unroll
    for (int i = 0; i < 4; ++i) {
        const int mb = m0 + wr * 64 + i * 16 + (lane >> 4) * 4;
        #pragma unroll
        for (int r = 0; r < 4; ++r) {
            const int m = mb + r;
            #pragma unroll
            for (int j = 0; j < 4; ++j) {
                const int n = n0 + wc * 64 + j * 16 + (lane & 15);
                const float s = acc[i][j][r];
                const bf16 hi = (bf16)s;
                Tp[(size_t)m * 1024 + n] = hi;
                Tp[(size_t)m * 1024 + 512 + n] = (bf16)(s - (float)hi);
            }
        }
    }
}

// ---------------------------------------------------------------------------
// Generic 128x128 GEMM, K=512 (proj): fp32 out.
// ---------------------------------------------------------------------------
__global__ __launch_bounds__(256) void gemm128_kernel(
    const bf16* __restrict__ A, const bf16* __restrict__ Bt,
    const float* __restrict__ bias, float* __restrict__ Cf,
    int ncols, int c_rows, size_t a_bstride, size_t bt_bstride)
{
    const int b  = blockIdx.z;
    const int m0 = blockIdx.y * 128;
    const int n0 = blockIdx.x * 128;
    const bf16* Ap = A  + (size_t)b * a_bstride;
    const bf16* Bp = Bt + (size_t)b * bt_bstride;

    __shared__ bf16 smem[16384];

    const int t    = threadIdx.x;
    const int lane = t & 63;
    const int wave = t >> 6;
    const int wr   = wave >> 1, wc = wave & 1;

    f32x4 acc[4][4];
    const f32x4 zf = {0.f, 0.f, 0.f, 0.f};
    #pragma unroll
    for (int i = 0; i < 4; ++i)
        #pragma unroll
        for (int j = 0; j < 4; ++j) acc[i][j] = zf;

    auto STAGE = [&](int p, int k0) {
        #pragma unroll
        for (int i = 0; i < 2; ++i) {
            const int c   = t + 256 * i;
            const int row = c >> 2;
            const int kb  = ((c & 3) ^ ((row >> 1) & 3)) * 8;
            __builtin_amdgcn_global_load_lds(
                (const AS1 void*)(Ap + (size_t)(m0 + row) * KDEPTH + k0 + kb),
                (AS3 void*)(smem + p * 8192 + c * 8), 16, 0, 0);
            __builtin_amdgcn_global_load_lds(
                (const AS1 void*)(Bp + (size_t)(n0 + row) * KDEPTH + k0 + kb),
                (AS3 void*)(smem + p * 8192 + 4096 + c * 8), 16, 0, 0);
        }
    };

    STAGE(0, 0);
    __syncthreads();
    int cur = 0;

    for (int kt = 0; kt < KDEPTH / 32; ++kt) {
        if (kt < KDEPTH / 32 - 1) STAGE(cur ^ 1, (kt + 1) * 32);

        const bf16* AsP = smem + cur * 8192;
        const bf16* BsP = AsP + 4096;
        bf16x8 af[4], bfv[4];
        #pragma unroll
        for (int i = 0; i < 4; ++i) {
            const int ar = wr * 64 + i * 16 + (lane & 15);
            const int ja = (lane >> 4) ^ ((ar >> 1) & 3);
            af[i]  = *(const bf16x8*)(AsP + ar * 32 + ja * 8);
            const int br = wc * 64 + i * 16 + (lane & 15);
            const int jb = (lane >> 4) ^ ((br >> 1) & 3);
            bfv[i] = *(const bf16x8*)(BsP + br * 32 + jb * 8);
        }
        #pragma unroll
        for (int i = 0; i < 4; ++i)
            #pragma unroll
            for (int j = 0; j < 4; ++j)
                acc[i][j] = __builtin_amdgcn_mfma_f32_16x16x32_bf16(
                    af[i], bfv[j], acc[i][j], 0, 0, 0);

        __syncthreads();
        cur ^= 1;
    }

    #pragma unroll
    for (int i = 0; i < 4; ++i) {
        const int mb = m0 + wr * 64 + i * 16 + (lane >> 4) * 4;
        #pragma unroll
        for (int r = 0; r < 4; ++r) {
            const int m  = mb + r;
            const float bv = bias ? bias[m] : 0.f;
            #pragma unroll
            for (int j = 0; j < 4; ++j) {
                const int n = n0 + wc * 64 + j * 16 + (lane & 15);
                Cf[(size_t)b * c_rows * ncols + (size_t)m * ncols + n] =
                    acc[i][j][r] + bv;
            }
        }
    }
}

// ---------------------------------------------------------------------------
// V GEMM with fused transpose epilogue: vt[b][n][m0+..] bf16.
// ---------------------------------------------------------------------------
__global__ __launch_bounds__(256) void gemm_vt_kernel(
    const bf16* __restrict__ A, const bf16* __restrict__ Bt,
    const float* __restrict__ bias, bf16* __restrict__ vt)
{
    const int b  = blockIdx.z;
    const int m0 = blockIdx.y * 128;
    const int n0 = blockIdx.x * 128;
    const bf16* Ap = A;
    const bf16* Bp = Bt + (size_t)b * NPIX * KDEPTH;

    __shared__ bf16 smem[16384];

    const int t    = threadIdx.x;
    const int lane = t & 63;
    const int wave = t >> 6;
    const int wr   = wave >> 1, wc = wave & 1;

    f32x4 acc[4][4];
    const f32x4 zf = {0.f, 0.f, 0.f, 0.f};
    #pragma unroll
    for (int i = 0; i < 4; ++i)
        #pragma unroll
        for (int j = 0; j < 4; ++j) acc[i][j] = zf;

    auto STAGE = [&](int p, int k0) {
        #pragma unroll
        for (int i = 0; i < 2; ++i) {
            const int c   = t + 256 * i;
            const int row = c >> 2;
            const int kb  = ((c & 3) ^ ((row >> 1) & 3)) * 8;
            __builtin_amdgcn_global_load_lds(
                (const AS1 void*)(Ap + (size_t)(m0 + row) * KDEPTH + k0 + kb),
                (AS3 void*)(smem + p * 8192 + c * 8), 16, 0, 0);
            __builtin_amdgcn_global_load_lds(
                (const AS1 void*)(Bp + (size_t)(n0 + row) * KDEPTH + k0 + kb),
                (AS3 void*)(smem + p * 8192 + 4096 + c * 8), 16, 0, 0);
        }
    };

    STAGE(0, 0);
    __syncthreads();
    int cur = 0;

    for (int kt = 0; kt < KDEPTH / 32; ++kt) {
        if (kt < KDEPTH / 32 - 1) STAGE(cur ^ 1, (kt + 1) * 32);

        const bf16* AsP = smem + cur * 8192;
        const bf16* BsP = AsP + 4096;
        bf16x8 af[4], bfv[4];
        #pragma unroll
        for (int i = 0; i < 4; ++i) {
            const int ar = wr * 64 + i * 16 + (lane & 15);
            const int ja = (lane >> 4) ^ ((ar >> 1) & 3);
            af[i]  = *(const bf16x8*)(AsP + ar * 32 + ja * 8);
            const int br = wc * 64 + i * 16 + (lane & 15);
            const int jb = (lane >> 4) ^ ((br >> 1) & 3);
            bfv[i] = *(const bf16x8*)(BsP + br * 32 + jb * 8);
        }
        #pragma unroll
        for (int i = 0; i < 4; ++i)
            #pragma unroll
            for (int j = 0; j < 4; ++j)
                acc[i][j] = __builtin_amdgcn_mfma_f32_16x16x32_bf16(
                    af[i], bfv[j], acc[i][j], 0, 0, 0);

        __syncthreads();
        cur ^= 1;
    }

    bf16* vb = vt + (size_t)b * NPIX * KDEPTH;
    bf16* tb = smem;
    #pragma unroll
    for (int p = 0; p < 2; ++p) {
        if (wc == p) {
            #pragma unroll
            for (int i = 0; i < 4; ++i) {
                const int ml = wr * 64 + i * 16 + (lane >> 4) * 4;
                #pragma unroll
                for (int j = 0; j < 4; ++j) {
                    const int ns = j * 16 + (lane & 15);
                    bf16x4 pk;
                    #pragma unroll
                    for (int r = 0; r < 4; ++r)
                        pk[r] = (bf16)(acc[i][j][r] + bias[m0 + ml + r]);
                    *(bf16x4*)(tb + ns * 132 + ml) = pk;
                }
            }
        }
        __syncthreads();
        #pragma unroll
        for (int ii = 0; ii < 4; ++ii) {
            const int lin = t + 256 * ii;
            const int row = lin >> 4;
            const int seg = lin & 15;
            const int4 v = *(const int4*)(tb + row * 132 + seg * 8);
            *(int4*)(vb + (size_t)(n0 + p * 64 + row) * KDEPTH + m0 + seg * 8) = v;
        }
        __syncthreads();
    }
}

// ---------------------------------------------------------------------------
// S + softmax: per (b,h): S = (T2hi+T2lo)·Wk^T + bq·kv^T + qv·bk^T, softmax.
// K=1024 over T2pair rows; Wk k-index wraps &511.
// ---------------------------------------------------------------------------
__global__ __launch_bounds__(256) void s_softmax_kernel(
    const bf16* __restrict__ T2pair, const bf16* __restrict__ wfull,
    const float* __restrict__ qkv_b, const float* __restrict__ xsum,
    float* __restrict__ attn)
{
    const int bh = blockIdx.x;
    const int b = bh >> 3, h = bh & 7;
    const bf16* qbase = T2pair + ((size_t)b * CH + h * HDIM) * 1024;  // T2 rows d
    const bf16* kbase = wfull + (size_t)(CH + h * HDIM) * CH;          // Wk rows e

    __shared__ bf16 smem[16384];
    __shared__ float xs[512], qv[64], kv[64], bqs[64], bks[64];

    const int t    = threadIdx.x;
    const int lane = t & 63;
    const int wave = t >> 6;

    for (int i = t; i < 512; i += 256) xs[i] = xsum[b * CH + i];
    if (t < 64) {
        bqs[t] = qkv_b[h * HDIM + t];
        bks[t] = qkv_b[CH + h * HDIM + t];
    }
    __syncthreads();
    if (t < 128) {
        const int e = t & 63;
        const bf16* wrow = wfull + (size_t)((t < 64 ? 0 : CH) + h * HDIM + e) * CH;
        float s = 0.f;
        for (int c = 0; c < 512; ++c) s += (float)wrow[c] * xs[c];
        if (t < 64) qv[e] = s;                              // (Wq xsum)[d]
        else        kv[e] = s + 4096.f * bks[e];            // (Wk xsum)[e] + N bk
    }

    f32x4 acc[4];
    const f32x4 zf = {0.f, 0.f, 0.f, 0.f};
    #pragma unroll
    for (int j = 0; j < 4; ++j) acc[j] = zf;

    auto STAGE = [&](int p, int k0) {
        #pragma unroll
        for (int i = 0; i < 2; ++i) {
            const int c   = t + 256 * i;
            const int row = c >> 3;
            const int nb  = ((c & 7) ^ (row & 7)) * 8;
            __builtin_amdgcn_global_load_lds(
                (const AS1 void*)(qbase + (size_t)row * 1024 + k0 + nb),
                (AS3 void*)(smem + p * 8192 + c * 8), 16, 0, 0);
            __builtin_amdgcn_global_load_lds(
                (const AS1 void*)(kbase + (size_t)row * CH + ((k0 + nb) & 511)),
                (AS3 void*)(smem + p * 8192 + 4096 + c * 8), 16, 0, 0);
        }
    };

    STAGE(0, 0);
    __syncthreads();
    int cur = 0;

    for (int nc = 0; nc < 16; ++nc) {
        if (nc < 15) STAGE(cur ^ 1, (nc + 1) * 64);

        const bf16* Qs = smem + cur * 8192;
        const bf16* Ks = Qs + 4096;
        #pragma unroll
        for (int ks = 0; ks < 2; ++ks) {
            const int dr = wave * 16 + (lane & 15);
            const int ja = (ks * 4 + (lane >> 4)) ^ (dr & 7);
            const bf16x8 af = *(const bf16x8*)(Qs + dr * 64 + ja * 8);
            #pragma unroll
            for (int j = 0; j < 4; ++j) {
                const int er = j * 16 + (lane & 15);
                const int jb = (ks * 4 + (lane >> 4)) ^ (er & 7);
                const bf16x8 bf_ = *(const bf16x8*)(Ks + er * 64 + jb * 8);
                acc[j] = __builtin_amdgcn_mfma_f32_16x16x32_bf16(af, bf_, acc[j], 0, 0, 0);
            }
        }
        __syncthreads();
        cur ^= 1;
    }

    // rank-1 correction + row softmax + write
    #pragma unroll
    for (int r = 0; r < 4; ++r) {
        const int d = wave * 16 + (lane >> 4) * 4 + r;
        float row4[4];
        #pragma unroll
        for (int j = 0; j < 4; ++j) {
            const int e = j * 16 + (lane & 15);
            row4[j] = acc[j][r] + bqs[d] * kv[e] + qv[d] * bks[e];
        }
        float m = fmaxf(fmaxf(row4[0], row4[1]), fmaxf(row4[2], row4[3]));
        m = fmaxf(m, __shfl_xor(m, 1));
        m = fmaxf(m, __shfl_xor(m, 2));
        m = fmaxf(m, __shfl_xor(m, 4));
        m = fmaxf(m, __shfl_xor(m, 8));
        float p4[4], sum = 0.f;
        #pragma unroll
        for (int j = 0; j < 4; ++j) { p4[j] = __expf((row4[j] - m) * SCALE); sum += p4[j]; }
        sum += __shfl_xor(sum, 1);
        sum += __shfl_xor(sum, 2);
        sum += __shfl_xor(sum, 4);
        sum += __shfl_xor(sum, 8);
        const float inv = 1.f / sum;
        #pragma unroll
        for (int j = 0; j < 4; ++j) {
            const int e = j * 16 + (lane & 15);
            attn[((size_t)bh * 64 + d) * 64 + e] = p4[j] * inv;
        }
    }
}

// ---------------------------------------------------------------------------
// attn_mean[b][d][e] = mean_h attn[b][h][d][e]
// ---------------------------------------------------------------------------
__global__ __launch_bounds__(256) void attn_mean_kernel(
    const float* __restrict__ attn, float* __restrict__ om)
{
    const int idx = blockIdx.x * 256 + threadIdx.x;
    const int b = idx >> 12, de = idx & 4095;
    float s = 0.f;
    #pragma unroll
    for (int h = 0; h < 8; ++h)
        s += attn[(((size_t)b * 8 + h) << 12) + de];
    om[idx] = s * 0.125f;
}

// ---------------------------------------------------------------------------
// W'[b][o][h*64+e] = sum_d proj_w[o][h*64+d] * attn[b,h,d,e]   (fp32 -> bf16)
// ---------------------------------------------------------------------------
__global__ __launch_bounds__(256) void wprime_kernel(
    const float* __restrict__ proj_w, const float* __restrict__ attn,
    bf16* __restrict__ wp)
{
    const int o0 = blockIdx.x * 64;
    const int h  = blockIdx.y;
    const int b  = blockIdx.z;

    __shared__ float ws[64][65];
    __shared__ float as_[64][65];

    const int t = threadIdx.x;
    #pragma unroll
    for (int i = 0; i < 4; ++i) {
        const int lin = t + 256 * i;
        const int r   = lin >> 4;
        const int c4  = (lin & 15) * 4;
        const float4 wv = *(const float4*)(proj_w + (size_t)(o0 + r) * CH + h * HDIM + c4);
        ws[r][c4 + 0] = wv.x; ws[r][c4 + 1] = wv.y;
        ws[r][c4 + 2] = wv.z; ws[r][c4 + 3] = wv.w;
        const float4 av = *(const float4*)(attn + (((size_t)(b * 8 + h) * 64) + r) * 64 + c4);
        as_[r][c4 + 0] = av.x; as_[r][c4 + 1] = av.y;
        as_[r][c4 + 2] = av.z; as_[r][c4 + 3] = av.w;
    }
    __syncthreads();

    const int tx = t & 15, ty = t >> 4;
    const int to = ty * 4, te = tx * 4;
    float acc[4][4] = {};
    for (int d = 0; d < 64; ++d) {
        float a[4], bb[4];
        #pragma unroll
        for (int i = 0; i < 4; ++i) a[i]  = ws[to + i][d];
        #pragma unroll
        for (int j = 0; j < 4; ++j) bb[j] = as_[d][te + j];
        #pragma unroll
        for (int i = 0; i < 4; ++i)
            #pragma unroll
            for (int j = 0; j < 4; ++j)
                acc[i][j] = fmaf(a[i], bb[j], acc[i][j]);
    }

    bf16* wb = wp + (size_t)b * CH * CH;
    #pragma unroll
    for (int i = 0; i < 4; ++i)
        #pragma unroll
        for (int j = 0; j < 4; ++j)
            wb[(size_t)(o0 + to + i) * CH + h * HDIM + te + j] = (bf16)acc[i][j];
}

// ---------------------------------------------------------------------------
extern "C" void kernel_launch(void* const* d_in, const int* in_sizes, int n_in,
                              void* d_out, int out_size, void* d_ws, size_t ws_size,
                              hipStream_t stream)
{
    (void)in_sizes; (void)n_in; (void)out_size;
    const float* x      = (const float*)d_in[0];
    const float* qkv_w  = (const float*)d_in[1];
    const float* qkv_b  = (const float*)d_in[2];
    const float* proj_w = (const float*)d_in[3];
    const float* proj_b = (const float*)d_in[4];

    float* out       = (float*)d_out;
    float* attn_mean = out + (size_t)BATCH * CH * NPIX;

    const size_t xt_bytes    = (size_t)BATCH * NPIX * CH * 2;          // 32 MiB
    const size_t xb_bytes    = (size_t)BATCH * CH * NPIX * 2;          // 32 MiB
    const size_t vt_bytes    = (size_t)BATCH * NPIX * CH * 2;          // 32 MiB
    const size_t gpart_bytes = (size_t)BATCH * GSPLIT * CH * CH * 4;   // 32 MiB
    const size_t G_bytes     = (size_t)BATCH * CH * 1024 * 2;          //  8 MiB (hi/lo)
    const size_t T2_bytes    = (size_t)BATCH * CH * 1024 * 2;          //  8 MiB (hi/lo)
    const size_t wq_bytes    = (size_t)OC3 * KDEPTH * 2;               // 1.5 MiB
    const size_t attn_bytes  = (size_t)BATCH * HEADS * HDIM * HDIM * 4;//  1 MiB
    const size_t wp_bytes    = (size_t)BATCH * CH * CH * 2;            //  4 MiB
    const size_t xsum_bytes  = (size_t)BATCH * CH * 4;                 // 16 KiB
    const size_t need = xt_bytes + xb_bytes + vt_bytes + gpart_bytes + G_bytes +
                        T2_bytes + wq_bytes + attn_bytes + wp_bytes + xsum_bytes;
    if (ws_size < need) {
        fprintf(stderr, "[kernel_launch] ws_size=%zu < need=%zu — abort\n", ws_size, need);
        fflush(stderr);
        return;
    }

    char* p = (char*)d_ws;
    bf16*  xt     = (bf16*)p;             p += xt_bytes;
    bf16*  xb     = (bf16*)p;             p += xb_bytes;
    bf16*  vt     = (bf16*)p;             p += vt_bytes;
    float* gpart  = (float*)p;            p += gpart_bytes;
    bf16*  Gpair  = (bf16*)p;             p += G_bytes;
    bf16*  T2pair = (bf16*)p;             p += T2_bytes;
    bf16*  wq_b   = (bf16*)p;             p += wq_bytes;
    float* attn   = (float*)p;            p += attn_bytes;
    bf16*  wprime = (bf16*)p;             p += wp_bytes;
    float* xsum   = (float*)p;

    // 0) weight convert (Wq, Wk, Wv)
    convert_bf16_kernel<<<dim3((OC3 * KDEPTH + 255) / 256), 256, 0, stream>>>(
        qkv_w, wq_b, OC3 * KDEPTH);

    // 1) x -> xt (transpose) + xb (flat), bf16
    transpose_convert_dual_kernel<<<dim3(NPIX / 64, CH / 64, BATCH), 256, 0, stream>>>(
        x, xt, xb);

    // 2) xsum[b][c]
    xsum_kernel<<<dim3(BATCH * CH), 256, 0, stream>>>(x, xsum);

    // 3) Gram: G = x x^T (split-K) then reduce -> hi/lo bf16 pair
    gram_partial_kernel<<<dim3(CH / 128, CH / 128, BATCH * GSPLIT), 256, 0, stream>>>(
        xb, gpart);
    gram_reduce_kernel<<<dim3(BATCH * CH * CH / 256), 256, 0, stream>>>(gpart, Gpair);

    // 4) T2 = Wq · G  (K=1024 hi/lo, out hi/lo)
    t2_gemm_kernel<<<dim3(CH / 128, CH / 128, BATCH), 256, 0, stream>>>(
        wq_b, Gpair, T2pair);

    // 5) S = T2 · Wk^T + rank-1 bias terms, softmax -> attn
    s_softmax_kernel<<<dim3(BATCH * HEADS), 256, 0, stream>>>(
        T2pair, wq_b, qkv_b, xsum, attn);

    // 6) attn mean over heads (output 1)
    attn_mean_kernel<<<dim3(BATCH * HDIM * HDIM / 256), 256, 0, stream>>>(attn, attn_mean);

    // 7) W' = proj_w · blockdiag(attn)
    wprime_kernel<<<dim3(CH / 64, HEADS, BATCH), 256, 0, stream>>>(proj_w, attn, wprime);

    // 8) V GEMM (fused vt transpose)
    gemm_vt_kernel<<<dim3(NPIX / 128, CH / 128, BATCH), 256, 0, stream>>>(
        wq_b + (size_t)2 * CH * KDEPTH, xt, qkv_b + 2 * CH, vt);

    // 9) proj: out = W'_b · V_b + proj_b (fp32)
    gemm128_kernel<<<dim3(NPIX / 128, CH / 128, BATCH), 256, 0, stream>>>(
        wprime, vt, proj_b, out, NPIX, CH, (size_t)CH * CH, (size_t)NPIX * KDEPTH);
}